// Round 10
// baseline (154.191 us; speedup 1.0000x reference)
//
#include <hip/hip_runtime.h>

#define NN   128
#define NB   512
#define NMAT 2560
#define L2E  1.4426950408889634f

typedef __attribute__((ext_vector_type(4))) float  f32x4;
typedef __attribute__((ext_vector_type(8))) short  short8;
typedef __attribute__((ext_vector_type(8))) ushort u16x8;

__device__ __forceinline__ float fexp2(float x){ return __builtin_amdgcn_exp2f(x); }
__device__ __forceinline__ float flog2(float x){ return __builtin_amdgcn_logf(x); }
__device__ __forceinline__ float frcp (float x){ return __builtin_amdgcn_rcpf(x); }

__device__ __forceinline__ ushort f2bf(float f){
    unsigned u = __float_as_uint(f);
    unsigned r = (u + 0x7FFFu + ((u >> 16) & 1u)) >> 16;
    return (ushort)r;
}
__device__ __forceinline__ float bf2f(ushort h){ return __uint_as_float(((unsigned)h) << 16); }

// 16-lane-group reductions (lane bits 0..3) — proven __shfl_xor forms
__device__ __forceinline__ float red16(float x){
#pragma unroll
    for (int s = 1; s < 16; s <<= 1) x += __shfl_xor(x, s);
    return x;
}
__device__ __forceinline__ float rmax16(float x){
#pragma unroll
    for (int s = 1; s < 16; s <<= 1) x = fmaxf(x, __shfl_xor(x, s));
    return x;
}

// ---------------------------------------------------------------------------
// Prep: permute w2*log2e into MFMA B-fragment order, split bf16 hi/lo.
// ---------------------------------------------------------------------------
__global__ __launch_bounds__(256) void prep_kernel(
    const float* __restrict__ w2, const float* __restrict__ b2,
    ushort* __restrict__ Bhi, ushort* __restrict__ Blo, float* __restrict__ b2s)
{
    int fid = blockIdx.x * 256 + threadIdx.x;    // 0..2047
    int ct = fid >> 8, ks = (fid >> 6) & 3, lane = fid & 63;
    int c  = ct * 16 + (lane & 15);
    int k0 = ks * 32 + ((lane >> 4) << 3);
    u16x8 hi, lo;
#pragma unroll
    for (int j = 0; j < 8; j++) {
        float v = w2[c * NN + k0 + j] * L2E;
        ushort h = f2bf(v);
        hi[j] = h;
        lo[j] = f2bf(v - bf2f(h));
    }
    *(u16x8*)(Bhi + (size_t)fid * 8) = hi;
    *(u16x8*)(Blo + (size_t)fid * 8) = lo;
    if (fid < NN) b2s[fid] = b2[fid] * L2E;
}

// ---------------------------------------------------------------------------
// Fused: MLP (MFMA builtin, split bf16) -> E init -> 10x Sinkhorn -> store^T.
// NO inline asm anywhere: MFMA via __builtin_amdgcn_mfma_f32_16x16x32_bf16
// (compiler inserts all required hazard wait-states — the inline-asm MFMA of
// R6-R9 was invisible to the hazard recognizer and corrupted acc under
// register pressure). Transcendentals via __builtin_amdgcn_{exp2,log,rcp}f.
// ---------------------------------------------------------------------------
__global__ __launch_bounds__(512, 4) void fused_kernel(
    const float* __restrict__ x,   const float* __restrict__ w1,
    const float* __restrict__ b1,  const ushort* __restrict__ Bhi,
    const ushort* __restrict__ Blo, const float* __restrict__ b2s,
    const float* __restrict__ noise, float* __restrict__ out)
{
    __shared__ float part[8][132];
    __shared__ float tbufT[128];

    const int m    = blockIdx.x;          // 0..2559
    const int b    = m & (NB - 1);
    const int t    = threadIdx.x;
    const int w    = t >> 6;              // wave 0..7
    const int lane = t & 63;
    const int h    = lane >> 4;
    const int cc   = lane & 15;

    const float* nb = noise + (size_t)m * NN * NN;
    float* ob       = out   + (size_t)m * NN * NN;

    // -------- A fragments: row = cc, k = 8h+v (proven R2-R5 pattern) --------
    const float xv = x[b * NN + 16 * w + cc];

    short8 Ahi[4], Alo[4];
#pragma unroll
    for (int ks = 0; ks < 4; ks++) {
        const int l0 = ks * 32 + (h << 3);
        float4 w1a = *(const float4*)(w1 + l0);
        float4 w1b = *(const float4*)(w1 + l0 + 4);
        float4 b1a = *(const float4*)(b1 + l0);
        float4 b1b = *(const float4*)(b1 + l0 + 4);
        float hv[8];
        hv[0] = fmaxf(fmaf(xv, w1a.x, b1a.x), 0.f);
        hv[1] = fmaxf(fmaf(xv, w1a.y, b1a.y), 0.f);
        hv[2] = fmaxf(fmaf(xv, w1a.z, b1a.z), 0.f);
        hv[3] = fmaxf(fmaf(xv, w1a.w, b1a.w), 0.f);
        hv[4] = fmaxf(fmaf(xv, w1b.x, b1b.x), 0.f);
        hv[5] = fmaxf(fmaf(xv, w1b.y, b1b.y), 0.f);
        hv[6] = fmaxf(fmaf(xv, w1b.z, b1b.z), 0.f);
        hv[7] = fmaxf(fmaf(xv, w1b.w, b1b.w), 0.f);
#pragma unroll
        for (int j = 0; j < 8; j++) {
            ushort hb = f2bf(hv[j]);
            Ahi[ks][j] = (short)hb;
            Alo[ks][j] = (short)f2bf(hv[j] - bf2f(hb));
        }
    }

    f32x4 acc[8];
#pragma unroll
    for (int ct = 0; ct < 8; ct++) acc[ct] = (f32x4){0.f, 0.f, 0.f, 0.f};

#pragma unroll
    for (int ks = 0; ks < 4; ks++) {
#pragma unroll
        for (int ct = 0; ct < 8; ct++) {
            const size_t off = ((size_t)(ct * 4 + ks) * 64 + lane) * 8;
            short8 bh = *(const short8*)(Bhi + off);
            short8 bl = *(const short8*)(Blo + off);
            acc[ct] = __builtin_amdgcn_mfma_f32_16x16x32_bf16(Ahi[ks], bh, acc[ct], 0, 0, 0);
            acc[ct] = __builtin_amdgcn_mfma_f32_16x16x32_bf16(Ahi[ks], bl, acc[ct], 0, 0, 0);
            acc[ct] = __builtin_amdgcn_mfma_f32_16x16x32_bf16(Alo[ks], bh, acc[ct], 0, 0, 0);
        }
    }

    // noise loads
    float E[8][4];
#pragma unroll
    for (int ct = 0; ct < 8; ct++)
#pragma unroll
        for (int q = 0; q < 4; q++)
            E[ct][q] = nb[(size_t)(16 * w + 4 * h + q) * NN + 16 * ct + cc];

    // E = la + noise*log2e  (la = acc + b2s; all pre-scaled by log2e)
#pragma unroll
    for (int ct = 0; ct < 8; ct++) {
        float bb = b2s[16 * ct + cc];
#pragma unroll
        for (int q = 0; q < 4; q++)
            E[ct][q] = fmaf(E[ct][q], L2E, acc[ct][q] + bb);
    }

    // init: row logsumexp2 (max-stabilized); E = 2^(y0 - R1) <= 1
#pragma unroll
    for (int q = 0; q < 4; q++) {
        float mx = E[0][q];
#pragma unroll
        for (int ct = 1; ct < 8; ct++) mx = fmaxf(mx, E[ct][q]);
        mx = rmax16(mx);
        float sm = 0.f;
#pragma unroll
        for (int ct = 0; ct < 8; ct++) sm += fexp2(E[ct][q] - mx);
        sm = red16(sm);
        float R1 = mx + flog2(sm);
#pragma unroll
        for (int ct = 0; ct < 8; ct++) E[ct][q] = fexp2(E[ct][q] - R1);
    }

    float u[4];
#pragma unroll
    for (int q = 0; q < 4; q++) u[q] = 1.f;
    float tj[8];

    for (int k = 0; k < 10; k++) {
        // ---- column pass: t[c] = 1 / sum_r E*u ----
        float loc[8];
#pragma unroll
        for (int ct = 0; ct < 8; ct++) {
            float s = 0.f;
#pragma unroll
            for (int q = 0; q < 4; q++) s = fmaf(E[ct][q], u[q], s);
            s += __shfl_xor(s, 16);      // band reduce over h
            s += __shfl_xor(s, 32);
            loc[ct] = s;
        }
        if (lane < 16) {
            *(float4*)&part[w][cc * 8]     = make_float4(loc[0], loc[1], loc[2], loc[3]);
            *(float4*)&part[w][cc * 8 + 4] = make_float4(loc[4], loc[5], loc[6], loc[7]);
        }
        __syncthreads();
        if (t < NN) {
            float cs = part[0][t];
#pragma unroll
            for (int p = 1; p < 8; p++) cs += part[p][t];
            tbufT[t] = frcp(cs);
        }
        __syncthreads();
        {
            float4 t0 = *(const float4*)&tbufT[cc * 8];
            float4 t1 = *(const float4*)&tbufT[cc * 8 + 4];
            tj[0] = t0.x; tj[1] = t0.y; tj[2] = t0.z; tj[3] = t0.w;
            tj[4] = t1.x; tj[5] = t1.y; tj[6] = t1.z; tj[7] = t1.w;
        }
        // ---- row pass: u[r] = 1 / sum_c E*t (skipped after last col pass) --
        if (k < 9) {
#pragma unroll
            for (int q = 0; q < 4; q++) {
                float s = 0.f;
#pragma unroll
                for (int ct = 0; ct < 8; ct++) s = fmaf(E[ct][q], tj[ct], s);
                u[q] = frcp(red16(s));
            }
        }
    }

    // output (transposed): out[m][c][r] = E[r][c]*u[r]*t[c]
#pragma unroll
    for (int ct = 0; ct < 8; ct++) {
        float4 v;
        v.x = E[ct][0] * u[0] * tj[ct];
        v.y = E[ct][1] * u[1] * tj[ct];
        v.z = E[ct][2] * u[2] * tj[ct];
        v.w = E[ct][3] * u[3] * tj[ct];
        *(float4*)(ob + (size_t)(16 * ct + cc) * NN + 16 * w + 4 * h) = v;
    }
}

extern "C" void kernel_launch(void* const* d_in, const int* in_sizes, int n_in,
                              void* d_out, int out_size, void* d_ws, size_t ws_size,
                              hipStream_t stream) {
    const float* x     = (const float*)d_in[0];
    const float* w1    = (const float*)d_in[1];
    const float* b1    = (const float*)d_in[2];
    const float* w2    = (const float*)d_in[3];
    const float* b2    = (const float*)d_in[4];
    const float* noise = (const float*)d_in[5];
    float* out = (float*)d_out;

    char* ws  = (char*)d_ws;
    ushort* Bhi = (ushort*)ws;                // 32 KB
    ushort* Blo = (ushort*)(ws + 32768);      // 32 KB
    float*  b2s = (float*)(ws + 65536);       // 512 B

    hipLaunchKernelGGL(prep_kernel, dim3(8), dim3(256), 0, stream,
                       w2, b2, Bhi, Blo, b2s);
    hipLaunchKernelGGL(fused_kernel, dim3(NMAT), dim3(512), 0, stream,
                       x, w1, b1, Bhi, Blo, b2s, noise, out);
}

// Round 11
// 137.962 us; speedup vs baseline: 1.1176x; 1.1176x over previous
//
#include <hip/hip_runtime.h>

#define NN   128
#define NB   512
#define NMAT 2560
#define L2E  1.4426950408889634f

typedef __attribute__((ext_vector_type(4))) float  f32x4;
typedef __attribute__((ext_vector_type(8))) short  short8;
typedef __attribute__((ext_vector_type(8))) ushort u16x8;

__device__ __forceinline__ float fexp2(float x){ return __builtin_amdgcn_exp2f(x); }
__device__ __forceinline__ float flog2(float x){ return __builtin_amdgcn_logf(x); }
__device__ __forceinline__ float frcp (float x){ return __builtin_amdgcn_rcpf(x); }

__device__ __forceinline__ ushort f2bf(float f){
    unsigned u = __float_as_uint(f);
    unsigned r = (u + 0x7FFFu + ((u >> 16) & 1u)) >> 16;
    return (ushort)r;
}
__device__ __forceinline__ float bf2f(ushort h){ return __uint_as_float(((unsigned)h) << 16); }

// ---- VALU-pipe reductions (DPP + permlane swaps) — no DS-pipe traffic ----
#define DPPMOV(x, ctrl) \
    __uint_as_float((unsigned)__builtin_amdgcn_update_dpp(0, (int)__float_as_uint(x), (ctrl), 0xF, 0xF, true))

// sum/max over lane bits 0..3 (16-lane groups); result in ALL 16 lanes.
__device__ __forceinline__ float red16(float x){
    x += DPPMOV(x, 0xB1);   // quad_perm [1,0,3,2]  : xor1
    x += DPPMOV(x, 0x4E);   // quad_perm [2,3,0,1]  : xor2
    x += DPPMOV(x, 0x141);  // row_half_mirror (x^7): combine quads
    x += DPPMOV(x, 0x140);  // row_mirror     (x^15): combine 8-halves
    return x;
}
__device__ __forceinline__ float rmax16(float x){
    x = fmaxf(x, DPPMOV(x, 0xB1));
    x = fmaxf(x, DPPMOV(x, 0x4E));
    x = fmaxf(x, DPPMOV(x, 0x141));
    x = fmaxf(x, DPPMOV(x, 0x140));
    return x;
}
// sum over lane bits 4,5 via gfx950 permlane swaps (VALU).
// swap(x,x) returns {x[lane], x[lane^K]} split across the two words -> sum.
__device__ __forceinline__ float bandsum(float x){
    unsigned xi = __float_as_uint(x);
    auto r16 = __builtin_amdgcn_permlane16_swap(xi, xi, false, false);
    float a = __uint_as_float(r16[0]) + __uint_as_float(r16[1]);   // + x[lane^16]
    unsigned ai = __float_as_uint(a);
    auto r32 = __builtin_amdgcn_permlane32_swap(ai, ai, false, false);
    return __uint_as_float(r32[0]) + __uint_as_float(r32[1]);      // + x[lane^32]
}

// ---------------------------------------------------------------------------
// Prep: permute w2*log2e into MFMA B-fragment order, split bf16 hi/lo.
// ---------------------------------------------------------------------------
__global__ __launch_bounds__(256) void prep_kernel(
    const float* __restrict__ w2, const float* __restrict__ b2,
    ushort* __restrict__ Bhi, ushort* __restrict__ Blo, float* __restrict__ b2s)
{
    int fid = blockIdx.x * 256 + threadIdx.x;    // 0..2047
    int ct = fid >> 8, ks = (fid >> 6) & 3, lane = fid & 63;
    int c  = ct * 16 + (lane & 15);
    int k0 = ks * 32 + ((lane >> 4) << 3);
    u16x8 hi, lo;
#pragma unroll
    for (int j = 0; j < 8; j++) {
        float v = w2[c * NN + k0 + j] * L2E;
        ushort h = f2bf(v);
        hi[j] = h;
        lo[j] = f2bf(v - bf2f(h));
    }
    *(u16x8*)(Bhi + (size_t)fid * 8) = hi;
    *(u16x8*)(Blo + (size_t)fid * 8) = lo;
    if (fid < NN) b2s[fid] = b2[fid] * L2E;
}

// ---------------------------------------------------------------------------
// Fused: MLP (MFMA builtin) -> E init -> 10x Sinkhorn -> transposed store.
// R10 structure; ALL reductions moved to the VALU pipe:
//   red16/rmax16 = 4x DPP (quad_perm/mirrors), bandsum = permlane16/32_swap.
// DS pipe now carries only the cross-wave 8x128 partial + t broadcast.
// ---------------------------------------------------------------------------
__global__ __launch_bounds__(512, 4) void fused_kernel(
    const float* __restrict__ x,   const float* __restrict__ w1,
    const float* __restrict__ b1,  const ushort* __restrict__ Bhi,
    const ushort* __restrict__ Blo, const float* __restrict__ b2s,
    const float* __restrict__ noise, float* __restrict__ out)
{
    __shared__ float part[8][132];
    __shared__ float tbufT[128];

    const int m    = blockIdx.x;          // 0..2559
    const int b    = m & (NB - 1);
    const int t    = threadIdx.x;
    const int w    = t >> 6;              // wave 0..7
    const int lane = t & 63;
    const int h    = lane >> 4;
    const int cc   = lane & 15;

    const float* nb = noise + (size_t)m * NN * NN;
    float* ob       = out   + (size_t)m * NN * NN;

    // -------- A fragments: row = cc, k = 8h+v --------
    const float xv = x[b * NN + 16 * w + cc];

    short8 Ahi[4], Alo[4];
#pragma unroll
    for (int ks = 0; ks < 4; ks++) {
        const int l0 = ks * 32 + (h << 3);
        float4 w1a = *(const float4*)(w1 + l0);
        float4 w1b = *(const float4*)(w1 + l0 + 4);
        float4 b1a = *(const float4*)(b1 + l0);
        float4 b1b = *(const float4*)(b1 + l0 + 4);
        float hv[8];
        hv[0] = fmaxf(fmaf(xv, w1a.x, b1a.x), 0.f);
        hv[1] = fmaxf(fmaf(xv, w1a.y, b1a.y), 0.f);
        hv[2] = fmaxf(fmaf(xv, w1a.z, b1a.z), 0.f);
        hv[3] = fmaxf(fmaf(xv, w1a.w, b1a.w), 0.f);
        hv[4] = fmaxf(fmaf(xv, w1b.x, b1b.x), 0.f);
        hv[5] = fmaxf(fmaf(xv, w1b.y, b1b.y), 0.f);
        hv[6] = fmaxf(fmaf(xv, w1b.z, b1b.z), 0.f);
        hv[7] = fmaxf(fmaf(xv, w1b.w, b1b.w), 0.f);
#pragma unroll
        for (int j = 0; j < 8; j++) {
            ushort hb = f2bf(hv[j]);
            Ahi[ks][j] = (short)hb;
            Alo[ks][j] = (short)f2bf(hv[j] - bf2f(hb));
        }
    }

    f32x4 acc[8];
#pragma unroll
    for (int ct = 0; ct < 8; ct++) acc[ct] = (f32x4){0.f, 0.f, 0.f, 0.f};

#pragma unroll
    for (int ks = 0; ks < 4; ks++) {
#pragma unroll
        for (int ct = 0; ct < 8; ct++) {
            const size_t off = ((size_t)(ct * 4 + ks) * 64 + lane) * 8;
            short8 bh = *(const short8*)(Bhi + off);
            short8 bl = *(const short8*)(Blo + off);
            acc[ct] = __builtin_amdgcn_mfma_f32_16x16x32_bf16(Ahi[ks], bh, acc[ct], 0, 0, 0);
            acc[ct] = __builtin_amdgcn_mfma_f32_16x16x32_bf16(Ahi[ks], bl, acc[ct], 0, 0, 0);
            acc[ct] = __builtin_amdgcn_mfma_f32_16x16x32_bf16(Alo[ks], bh, acc[ct], 0, 0, 0);
        }
    }

    // noise loads
    float E[8][4];
#pragma unroll
    for (int ct = 0; ct < 8; ct++)
#pragma unroll
        for (int q = 0; q < 4; q++)
            E[ct][q] = nb[(size_t)(16 * w + 4 * h + q) * NN + 16 * ct + cc];

    // E = la + noise*log2e  (la = acc + b2s; all pre-scaled by log2e)
#pragma unroll
    for (int ct = 0; ct < 8; ct++) {
        float bb = b2s[16 * ct + cc];
#pragma unroll
        for (int q = 0; q < 4; q++)
            E[ct][q] = fmaf(E[ct][q], L2E, acc[ct][q] + bb);
    }

    // init: row logsumexp2 (max-stabilized); E = 2^(y0 - R1) <= 1
#pragma unroll
    for (int q = 0; q < 4; q++) {
        float mx = E[0][q];
#pragma unroll
        for (int ct = 1; ct < 8; ct++) mx = fmaxf(mx, E[ct][q]);
        mx = rmax16(mx);
        float sm = 0.f;
#pragma unroll
        for (int ct = 0; ct < 8; ct++) sm += fexp2(E[ct][q] - mx);
        sm = red16(sm);
        float R1 = mx + flog2(sm);
#pragma unroll
        for (int ct = 0; ct < 8; ct++) E[ct][q] = fexp2(E[ct][q] - R1);
    }

    float u[4];
#pragma unroll
    for (int q = 0; q < 4; q++) u[q] = 1.f;
    float tj[8];

    for (int k = 0; k < 10; k++) {
        // ---- column pass: t[c] = 1 / sum_r E*u ----
        float loc[8];
#pragma unroll
        for (int ct = 0; ct < 8; ct++) {
            float s = 0.f;
#pragma unroll
            for (int q = 0; q < 4; q++) s = fmaf(E[ct][q], u[q], s);
            loc[ct] = bandsum(s);          // sum over h (lane bits 4,5), VALU
        }
        if (lane < 16) {
            *(float4*)&part[w][cc * 8]     = make_float4(loc[0], loc[1], loc[2], loc[3]);
            *(float4*)&part[w][cc * 8 + 4] = make_float4(loc[4], loc[5], loc[6], loc[7]);
        }
        __syncthreads();
        if (t < NN) {
            float cs = part[0][t];
#pragma unroll
            for (int p = 1; p < 8; p++) cs += part[p][t];
            tbufT[t] = frcp(cs);
        }
        __syncthreads();
        {
            float4 t0 = *(const float4*)&tbufT[cc * 8];
            float4 t1 = *(const float4*)&tbufT[cc * 8 + 4];
            tj[0] = t0.x; tj[1] = t0.y; tj[2] = t0.z; tj[3] = t0.w;
            tj[4] = t1.x; tj[5] = t1.y; tj[6] = t1.z; tj[7] = t1.w;
        }
        // ---- row pass: u[r] = 1 / sum_c E*t (skipped after last col pass) --
        if (k < 9) {
#pragma unroll
            for (int q = 0; q < 4; q++) {
                float s = 0.f;
#pragma unroll
                for (int ct = 0; ct < 8; ct++) s = fmaf(E[ct][q], tj[ct], s);
                u[q] = frcp(red16(s));     // sum over cc (lane bits 0-3), VALU
            }
        }
    }

    // output (transposed): out[m][c][r] = E[r][c]*u[r]*t[c]
#pragma unroll
    for (int ct = 0; ct < 8; ct++) {
        float4 v;
        v.x = E[ct][0] * u[0] * tj[ct];
        v.y = E[ct][1] * u[1] * tj[ct];
        v.z = E[ct][2] * u[2] * tj[ct];
        v.w = E[ct][3] * u[3] * tj[ct];
        *(float4*)(ob + (size_t)(16 * ct + cc) * NN + 16 * w + 4 * h) = v;
    }
}

extern "C" void kernel_launch(void* const* d_in, const int* in_sizes, int n_in,
                              void* d_out, int out_size, void* d_ws, size_t ws_size,
                              hipStream_t stream) {
    const float* x     = (const float*)d_in[0];
    const float* w1    = (const float*)d_in[1];
    const float* b1    = (const float*)d_in[2];
    const float* w2    = (const float*)d_in[3];
    const float* b2    = (const float*)d_in[4];
    const float* noise = (const float*)d_in[5];
    float* out = (float*)d_out;

    char* ws  = (char*)d_ws;
    ushort* Bhi = (ushort*)ws;                // 32 KB
    ushort* Blo = (ushort*)(ws + 32768);      // 32 KB
    float*  b2s = (float*)(ws + 65536);       // 512 B

    hipLaunchKernelGGL(prep_kernel, dim3(8), dim3(256), 0, stream,
                       w2, b2, Bhi, Blo, b2s);
    hipLaunchKernelGGL(fused_kernel, dim3(NMAT), dim3(512), 0, stream,
                       x, w1, b1, Bhi, Blo, b2s, noise, out);
}